// Round 9
// baseline (39.224 us; speedup 1.0000x reference)
//
#include <hip/hip_runtime.h>
#include <hip/hip_fp16.h>
#include <float.h>

constexpr int KMAX  = 11;    // KS_MAX
constexpr int SEQ   = 512;   // SEQ_LEN
constexpr int NB    = 64;    // BATCH
constexpr int NBB   = 8;     // batches per main block (8 groups)
constexpr int NGRP  = NB / NBB;
constexpr int MSTR  = 32;    // meta ints per k: [0]=nj [1..11]=c [12..22]=w2bits
constexpr int WSLOT = 640;   // FIXED window: slot = s + 64, s in [-64, 576); 16 B/slot
constexpr int X0    = 64;    // slot of s=0
constexpr int WHI   = (WSLOT - 1) * 16;   // 10224: clamp-high byte addr (slot 639 = zero)

__device__ __forceinline__ unsigned h2b(__half2 h) { unsigned u; __builtin_memcpy(&u, &h, 4); return u; }
__device__ __forceinline__ __half2  b2h(unsigned u) { __half2 h; __builtin_memcpy(&h, &u, 4); return h; }

// ROCm 7.2 has no __hmax2/__hmin2 — use VOP3P directly.
__device__ __forceinline__ unsigned pkmax(unsigned a, unsigned b) {
    unsigned d; asm("v_pk_max_f16 %0, %1, %2" : "=v"(d) : "v"(a), "v"(b)); return d;
}
__device__ __forceinline__ unsigned pkadd(unsigned a, unsigned b) { return h2b(__hadd2(b2h(a), b2h(b))); }
__device__ __forceinline__ __half2 h2max(__half2 a, __half2 b) { return b2h(pkmax(h2b(a), h2b(b))); }
// fused (a*b+c) clamped to [0,1] — the whole count update in one VOP3P
__device__ __forceinline__ unsigned pkfma_clamp(unsigned a, unsigned b, unsigned c) {
    unsigned d; asm("v_pk_fma_f16 %0, %1, %2, %3 clamp" : "=v"(d) : "v"(a), "v"(b), "v"(c)); return d;
}

// DPP lane-exchange (VALU pipe, no LDS). Masked-out rows get `old` (identity).
template<int CTRL>
__device__ __forceinline__ unsigned dppmov(unsigned old, unsigned v) {
    return (unsigned)__builtin_amdgcn_update_dpp((int)old, (int)v, CTRL, 0xF, 0xF, false);
}
constexpr unsigned NEGINF2 = 0xFC00FC00u;   // -inf | -inf (f16 pair)

__device__ __forceinline__ unsigned dpp_redmax(unsigned x) {
    x = pkmax(x, dppmov<0xB1 >(NEGINF2, x));  // quad_perm xor1
    x = pkmax(x, dppmov<0x4E >(NEGINF2, x));  // quad_perm xor2
    x = pkmax(x, dppmov<0x141>(NEGINF2, x));  // row_half_mirror
    x = pkmax(x, dppmov<0x140>(NEGINF2, x));  // row_mirror
    x = pkmax(x, dppmov<0x142>(NEGINF2, x));  // row_bcast15
    x = pkmax(x, dppmov<0x143>(NEGINF2, x));  // row_bcast31
    return x;                                  // lane 63 valid
}
__device__ __forceinline__ unsigned dpp_redadd(unsigned x) {
    x = pkadd(x, dppmov<0xB1 >(0u, x));
    x = pkadd(x, dppmov<0x4E >(0u, x));
    x = pkadd(x, dppmov<0x141>(0u, x));
    x = pkadd(x, dppmov<0x140>(0u, x));
    x = pkadd(x, dppmov<0x142>(0u, x));
    x = pkadd(x, dppmov<0x143>(0u, x));
    return x;                                  // lane 63 valid
}

// ======================= prep kernel =======================
// blocks [0, K):    derive c_kj from idx ramp (single stride-16 probe; interior
//                   run of the clipped ramp is >=510 wide inside [0,maxL), so
//                   lane*16 sampling hits it in one read), compact nonzero taps.
// blocks [K, K+32): transpose+convert x (NB x SEQ f32) -> xt16[g][s][8] f16
__global__ __launch_bounds__(256)
void prep_kernel(const float* __restrict__ x, const float* __restrict__ w,
                 const int* __restrict__ idx, int* __restrict__ meta,
                 unsigned short* __restrict__ xt, int K, int maxL)
{
    const int tid = threadIdx.x;
    if ((int)blockIdx.x >= K) {
        const int j  = ((int)blockIdx.x - K) * 256 + tid;   // 0..8191
        const int b  = j >> 7;                              // 0..63
        const int s4 = j & 127;                             // 0..127
        const float4 v = reinterpret_cast<const float4*>(x)[b * (SEQ / 4) + s4];
        const int g = b >> 3, bl = b & 7;
        unsigned short* dst = xt + ((size_t)g * SEQ + s4 * 4) * NBB + bl;
        __half h;
        h = __float2half_rn(v.x); __builtin_memcpy(&dst[0 * NBB], &h, 2);
        h = __float2half_rn(v.y); __builtin_memcpy(&dst[1 * NBB], &h, 2);
        h = __float2half_rn(v.z); __builtin_memcpy(&dst[2 * NBB], &h, 2);
        h = __float2half_rn(v.w); __builtin_memcpy(&dst[3 * NBB], &h, 2);
        return;
    }

    __shared__ int c_sh[KMAX];
    const int k = blockIdx.x, wave = tid >> 6, lane = tid & 63;

    for (int j = wave; j < KMAX; j += 4) {
        const int* row = idx + ((size_t)k * KMAX + j) * (size_t)maxL;
        int c = 1 << 20;   // sentinel: clamp path reads zeros -> tap contributes 0
        // fast probe: one strided read covering t = 0,16,...,1008 (clamped to maxL-1)
        {
            const int t = min(lane * 16, maxL - 1);
            const int v = row[t];
            const bool interior = (v > 0) && (v < SEQ - 1);
            const unsigned long long mb = __ballot(interior);
            if (mb != 0ull) {
                const int fl = __builtin_ctzll(mb);
                const int tf = min(fl * 16, maxL - 1);
                c = __shfl(v, fl) - tf;
            } else {
                // fallback (degenerate taps): dense 64-wide scan
                for (int base = 0; base < maxL; base += 64) {
                    const int t2 = base + lane;
                    const int v2 = (t2 < maxL) ? row[t2] : 0;
                    const bool in2 = (v2 > 0) && (v2 < SEQ - 1);
                    const unsigned long long mb2 = __ballot(in2);
                    if (mb2 != 0ull) {
                        const int fl2 = __builtin_ctzll(mb2);
                        c = __shfl(v2, fl2) - (base + fl2);
                        break;
                    }
                }
            }
        }
        if (lane == 0) c_sh[j] = c;
    }
    __syncthreads();

    if (tid == 0) {
        int* mk = meta + (size_t)k * MSTR;
        int n = 0;
        for (int j = 0; j < KMAX; ++j) {
            const float wj = w[(size_t)k * KMAX + j];
            if (wj != 0.0f) {
                mk[1 + n] = c_sh[j];
                __half hw = __float2half_rn(wj);
                unsigned short ub; __builtin_memcpy(&ub, &hw, 2);
                mk[12 + n] = (unsigned)ub | ((unsigned)ub << 16);
                ++n;
            }
        }
        for (int jj = n; jj < KMAX; ++jj) { mk[1 + jj] = 1 << 20; mk[12 + jj] = 0; }
        mk[0] = n;
    }
}

// ======================= main kernel =======================
// grid (K, 8): block = (kernel k, 8-batch group). 256 threads = 4 waves.
// FIXED 640-slot LDS window (10.25 KB -> 8 blocks/CU = 32 waves): slot = s+64,
// zeros outside s in [0,512). Branchless conv: per-visit per-lane address CLAMP
// min(max(addr,0),10224) redirects out-of-window lanes to zeroed fringe slots
// (contribute exactly 0 == reference mask). All NJ ds_read_b128 issue
// back-to-back; count via clamped pk_fma; reductions on the VALU pipe (DPP).
template<int NJ>
__device__ __forceinline__ void conv_body(
    const char* __restrict__ xsc, const int* __restrict__ msh,
    int lout, int wave, int lane, unsigned ctermb,
    __half2 (&mx2)[4], __half2 (&ct2)[4])
{
    const __half2 zero2 = __float2half2_rn(0.f);
    const __half2 nbig2 = __float2half2_rn(-65504.f);
    const unsigned C4b  = 0x74007400u;   // f16 pair {2^14, 2^14}

    int sb[NJ]; __half2 wr[NJ];
#pragma unroll
    for (int j = 0; j < NJ; ++j) {
        const int c = __builtin_amdgcn_readfirstlane(msh[1 + j]);
        wr[j] = b2h((unsigned)__builtin_amdgcn_readfirstlane(msh[12 + j]));
        sb[j] = (wave * 64 + lane + X0 + c) * 16;   // byte addr at chunk 0
    }
#pragma unroll
    for (int m = 0; m < 4; ++m) { mx2[m] = nbig2; ct2[m] = zero2; }

#pragma unroll
    for (int it = 0; it < 4; ++it) {
        const int tb = wave * 64 + it * 256;
        if (tb + 64 <= lout) {             // wave-uniform SALU guard, full chunk
            uint4 d[NJ];
#pragma unroll
            for (int j = 0; j < NJ; ++j) {
                const int a = min(max(sb[j] + it * 4096, 0), WHI);
                d[j] = *reinterpret_cast<const uint4*>(xsc + a);
            }
            __half2 a4[4] = {zero2, zero2, zero2, zero2};
#pragma unroll
            for (int j = 0; j < NJ; ++j) {
                a4[0] = __hfma2(wr[j], b2h(d[j].x), a4[0]);
                a4[1] = __hfma2(wr[j], b2h(d[j].y), a4[1]);
                a4[2] = __hfma2(wr[j], b2h(d[j].z), a4[2]);
                a4[3] = __hfma2(wr[j], b2h(d[j].w), a4[3]);
            }
#pragma unroll
            for (int m = 0; m < 4; ++m) {
                mx2[m] = h2max(mx2[m], a4[m]);
                ct2[m] = b2h(pkadd(h2b(ct2[m]), pkfma_clamp(h2b(a4[m]), C4b, ctermb)));
            }
        }
    }

    const int rem = lout & 63;
    if (rem) {                              // partial chunk pc, owned by wave pc&3
        const int pc = lout >> 6;
        if ((pc & 3) == wave) {
            const int off = (pc >> 2) << 12;
            uint4 d[NJ];
#pragma unroll
            for (int j = 0; j < NJ; ++j) {
                const int a = min(max(sb[j] + off, 0), WHI);
                d[j] = *reinterpret_cast<const uint4*>(xsc + a);
            }
            __half2 a4[4] = {zero2, zero2, zero2, zero2};
#pragma unroll
            for (int j = 0; j < NJ; ++j) {
                a4[0] = __hfma2(wr[j], b2h(d[j].x), a4[0]);
                a4[1] = __hfma2(wr[j], b2h(d[j].y), a4[1]);
                a4[2] = __hfma2(wr[j], b2h(d[j].z), a4[2]);
                a4[3] = __hfma2(wr[j], b2h(d[j].w), a4[3]);
            }
            const bool tm = lane < rem;
#pragma unroll
            for (int m = 0; m < 4; ++m) {
                a4[m] = tm ? a4[m] : nbig2;   // -65504*2^14 -> -inf -> clamp -> 0
                mx2[m] = h2max(mx2[m], a4[m]);
                ct2[m] = b2h(pkadd(h2b(ct2[m]), pkfma_clamp(h2b(a4[m]), C4b, ctermb)));
            }
        }
    }
}

__global__ __launch_bounds__(256, 8)
void rocket_main(const unsigned short* __restrict__ xt, const int* __restrict__ meta,
                 const float* __restrict__ bias, const int* __restrict__ l_out,
                 float* __restrict__ out, int K)
{
    __shared__ __align__(16) unsigned xs_u[WSLOT * 4];   // 10240 B window
    __shared__ unsigned redm[4][4], redc[4][4];
    __shared__ int msh[MSTR];

    const int k    = blockIdx.x;
    const int grp  = blockIdx.y;
    const int tid  = threadIdx.x;
    const int wave = __builtin_amdgcn_readfirstlane(tid >> 6);
    const int lane = tid & 63;

    if (tid < MSTR) msh[tid] = meta[(size_t)k * MSTR + tid];

    // ---- stage: zero the 128 fringe slots + copy 512 real slots (all b128) ----
    float4* xs4 = reinterpret_cast<float4*>(xs_u);
    if (tid < 2 * X0) {
        const int slot = (tid < X0) ? tid : tid + SEQ;   // [0,64) and [576,640)
        xs4[slot] = make_float4(0.f, 0.f, 0.f, 0.f);
    }
    const float4* src = reinterpret_cast<const float4*>(xt + (size_t)grp * SEQ * NBB);
    xs4[X0 + tid]       = src[tid];
    xs4[X0 + 256 + tid] = src[256 + tid];
    __syncthreads();

    const int      nj     = __builtin_amdgcn_readfirstlane(msh[0]);
    const int      lout   = l_out[k];
    const float    biasf  = bias[k];
    const unsigned ctermb = h2b(__float2half2_rn(biasf * 16384.f));

    __half2 mx2[4], ct2[4];
    const char* xsc = reinterpret_cast<const char*>(xs_u);
    if (nj <= 7)      conv_body<7 >(xsc, msh, lout, wave, lane, ctermb, mx2, ct2);
    else if (nj <= 9) conv_body<9 >(xsc, msh, lout, wave, lane, ctermb, mx2, ct2);
    else              conv_body<11>(xsc, msh, lout, wave, lane, ctermb, mx2, ct2);

    // ---- 64-lane reduce on the VALU pipe (DPP); lane 63 holds the result ----
    unsigned um[4], uc[4];
#pragma unroll
    for (int m = 0; m < 4; ++m) {
        um[m] = dpp_redmax(h2b(mx2[m]));
        uc[m] = dpp_redadd(h2b(ct2[m]));
    }
    if (lane == 63) {
#pragma unroll
        for (int m = 0; m < 4; ++m) { redm[wave][m] = um[m]; redc[wave][m] = uc[m]; }
    }
    __syncthreads();

    if (tid < 16) {
        const int bl = tid >> 1, kind = tid & 1;     // batch-in-group, {max,ppv}
        const int m = bl >> 1, hi = bl & 1;
        const int b = grp * NBB + bl;
        if (kind == 0) {
            float v = -FLT_MAX;
#pragma unroll
            for (int wv = 0; wv < 4; ++wv) {
                const __half2 h = b2h(redm[wv][m]);
                v = fmaxf(v, hi ? __high2float(h) : __low2float(h));
            }
            out[(size_t)b * (2 * K) + 2 * k] = v + biasf;   // deferred bias
        } else {
            float s = 0.f;
#pragma unroll
            for (int wv = 0; wv < 4; ++wv) {
                const __half2 h = b2h(redc[wv][m]);
                s += hi ? __high2float(h) : __low2float(h);
            }
            out[(size_t)b * (2 * K) + 2 * k + 1] = s / (float)lout;
        }
    }
}

// ======================= launch =======================
extern "C" void kernel_launch(void* const* d_in, const int* in_sizes, int n_in,
                              void* d_out, int out_size, void* d_ws, size_t ws_size,
                              hipStream_t stream)
{
    const float* x    = (const float*)d_in[0];
    const float* w    = (const float*)d_in[1];
    const float* bias = (const float*)d_in[2];
    const int*   idx  = (const int*)d_in[3];
    // d_in[4] = valid (unused: validity derived exactly from the idx ramp)
    const int*   lout = (const int*)d_in[5];
    float* out = (float*)d_out;

    const int K    = in_sizes[2];               // N_KERNELS
    const int maxL = in_sizes[3] / (K * KMAX);  // idx = [K][KMAX][maxL]

    // workspace: meta (K*32 ints) | xt16 (NB*SEQ f16), 256B-aligned split
    int* meta = (int*)d_ws;
    size_t meta_bytes = ((size_t)K * MSTR * sizeof(int) + 255) & ~(size_t)255;
    unsigned short* xt = (unsigned short*)((char*)d_ws + meta_bytes);

    prep_kernel<<<K + 32, 256, 0, stream>>>(x, w, idx, meta, xt, K, maxL);
    rocket_main<<<dim3(K, NGRP), 256, 0, stream>>>(xt, meta, bias, lout, out, K);
}